// Round 2
// baseline (249.276 us; speedup 1.0000x reference)
//
#include <hip/hip_runtime.h>
#include <hip/hip_bf16.h>
#include <math.h>

#define B 4
#define TQ 512
#define TV 1024
#define DQ 256
#define DV 256
#define UNITS 64
#define QBLK 4
#define NTHREADS 512
#define NWAVES (NTHREADS / 64)

// 2*log2(e): exp(2x) == exp2(C*x)
#define CEXP 2.885390081777927f

__device__ __forceinline__ float wave_max(float v) {
    #pragma unroll
    for (int off = 32; off > 0; off >>= 1)
        v = fmaxf(v, __shfl_xor(v, off, 64));
    return v;
}
__device__ __forceinline__ float wave_sum(float v) {
    #pragma unroll
    for (int off = 32; off > 0; off >>= 1)
        v += __shfl_xor(v, off, 64);
    return v;
}

// out[m][u] = sum_d in[m][d] * w[d][u].  One wave per row (u = lane).
__global__ void proj_kernel(const float* __restrict__ in, const float* __restrict__ w,
                            float* __restrict__ out, int M) {
    int u = threadIdx.x & 63;
    int m = blockIdx.x * 4 + (threadIdx.x >> 6);
    if (m >= M) return;
    const float* row = in + (size_t)m * DQ;
    float acc = 0.f;
    #pragma unroll 8
    for (int d = 0; d < DQ; ++d)
        acc = fmaf(row[d], w[d * UNITS + u], acc);
    out[(size_t)m * UNITS + u] = acc;
}

__global__ __launch_bounds__(NTHREADS, 4) void attn_kernel(
        const float* __restrict__ qproj,   // [B*TQ, UNITS]
        const float* __restrict__ kproj,   // [B*TV, UNITS]
        const float* __restrict__ value,   // [B, TV, DV]
        const float* __restrict__ scale,   // [UNITS]
        float* __restrict__ out_ctx,       // [B*TQ, DV]
        float* __restrict__ out_attn) {    // [B*TQ, TV]
    __shared__ float q_lds[QBLK][UNITS];   // pre-scaled by CEXP
    __shared__ float scale_lds[UNITS];
    __shared__ float sc[QBLK][TV];         // scores -> attn (16 KB)
    __shared__ float red[NWAVES];
    __shared__ float sumscale_lds;

    const int tid  = threadIdx.x;
    const int lane = tid & 63;
    const int wid  = tid >> 6;

    // XCD-aware swizzle (grid = 512, divisible by 8, bijective)
    int bid = blockIdx.x;
    bid = (bid & 7) * (int)(gridDim.x >> 3) + (bid >> 3);

    const int b  = bid / (TQ / QBLK);
    const int q0 = (bid % (TQ / QBLK)) * QBLK;

    if (tid < QBLK * UNITS)
        q_lds[tid >> 6][tid & 63] =
            CEXP * qproj[((size_t)(b * TQ + q0) + (tid >> 6)) * UNITS + (tid & 63)];
    else if (tid < QBLK * UNITS + UNITS)
        scale_lds[tid - QBLK * UNITS] = scale[tid - QBLK * UNITS];
    __syncthreads();
    if (wid == 0) {
        float s = wave_sum(scale_lds[lane]);
        if (lane == 0) sumscale_lds = s;
    }
    __syncthreads();

    // ---- scores: thread owns one v per 512-tile; k row in registers ----
    const float* kb = kproj + (size_t)b * TV * UNITS;
    for (int tile = 0; tile < TV / NTHREADS; ++tile) {
        const int v = tile * NTHREADS + tid;
        float kr[UNITS];
        const float4* krow = (const float4*)(kb + (size_t)v * UNITS);
        #pragma unroll
        for (int i = 0; i < UNITS / 4; ++i) {
            float4 t = krow[i];
            kr[4*i+0] = CEXP * t.x; kr[4*i+1] = CEXP * t.y;
            kr[4*i+2] = CEXP * t.z; kr[4*i+3] = CEXP * t.w;
        }
        float acc0 = 0.f, acc1 = 0.f, acc2 = 0.f, acc3 = 0.f;
        #pragma unroll
        for (int u = 0; u < UNITS; ++u) {
            const float k  = kr[u];
            const float su = scale_lds[u];
            // tanh(x) = 1 - 2*rcp(exp2(C*x)+1); q,k pre-scaled by C
            float e0 = __expf(0.6931471805599453f * (q_lds[0][u] + k));
            float e1 = __expf(0.6931471805599453f * (q_lds[1][u] + k));
            float e2 = __expf(0.6931471805599453f * (q_lds[2][u] + k));
            float e3 = __expf(0.6931471805599453f * (q_lds[3][u] + k));
            acc0 = fmaf(su, __builtin_amdgcn_rcpf(e0 + 1.f), acc0);
            acc1 = fmaf(su, __builtin_amdgcn_rcpf(e1 + 1.f), acc1);
            acc2 = fmaf(su, __builtin_amdgcn_rcpf(e2 + 1.f), acc2);
            acc3 = fmaf(su, __builtin_amdgcn_rcpf(e3 + 1.f), acc3);
        }
        const float ss = sumscale_lds;
        sc[0][v] = ss - 2.f * acc0;
        sc[1][v] = ss - 2.f * acc1;
        sc[2][v] = ss - 2.f * acc2;
        sc[3][v] = ss - 2.f * acc3;
    }
    __syncthreads();

    // ---- softmax per q row + write attn (512 threads, 2 elems each) ----
    #pragma unroll 1
    for (int q = 0; q < QBLK; ++q) {
        float x0 = sc[q][tid], x1 = sc[q][tid + NTHREADS];
        float m = wave_max(fmaxf(x0, x1));
        if (lane == 0) red[wid] = m;
        __syncthreads();
        m = red[0];
        #pragma unroll
        for (int i = 1; i < NWAVES; ++i) m = fmaxf(m, red[i]);
        float e0 = __expf(x0 - m), e1 = __expf(x1 - m);
        float s = wave_sum(e0 + e1);
        __syncthreads();               // red reads (max) done before overwrite
        if (lane == 0) red[wid] = s;
        __syncthreads();
        s = red[0];
        #pragma unroll
        for (int i = 1; i < NWAVES; ++i) s += red[i];
        const float inv = 1.0f / s;
        float a0 = e0 * inv, a1 = e1 * inv;
        sc[q][tid] = a0;
        sc[q][tid + NTHREADS] = a1;
        float* arow = out_attn + (size_t)(b * TQ + q0 + q) * TV;
        arow[tid] = a0;
        arow[tid + NTHREADS] = a1;
        __syncthreads();               // before next q overwrites red
    }

    // ---- context: 2 half-blocks x (256 cols, 2 q-rows each) ----
    const int d  = tid & (DV - 1);
    const int qh = tid >> 8;           // 0 or 1
    const float* vb = value + (size_t)b * TV * DV;
    float acc0 = 0.f, acc1 = 0.f;
    #pragma unroll 8
    for (int v = 0; v < TV; ++v) {
        float val = vb[(size_t)v * DV + d];
        acc0 = fmaf(sc[qh * 2 + 0][v], val, acc0);
        acc1 = fmaf(sc[qh * 2 + 1][v], val, acc1);
    }
    out_ctx[(size_t)(b * TQ + q0 + qh * 2 + 0) * DV + d] = acc0;
    out_ctx[(size_t)(b * TQ + q0 + qh * 2 + 1) * DV + d] = acc1;
}

extern "C" void kernel_launch(void* const* d_in, const int* in_sizes, int n_in,
                              void* d_out, int out_size, void* d_ws, size_t ws_size,
                              hipStream_t stream) {
    const float* query = (const float*)d_in[0];
    const float* value = (const float*)d_in[1];
    const float* w1    = (const float*)d_in[2];
    const float* w2    = (const float*)d_in[3];
    const float* scale = (const float*)d_in[4];

    float* out      = (float*)d_out;
    float* out_ctx  = out;                         // [B*TQ*DV]
    float* out_attn = out + (size_t)B * TQ * DV;   // [B*TQ*TV]

    float* qproj = (float*)d_ws;                   // B*TQ*UNITS floats
    float* kproj = qproj + (size_t)B * TQ * UNITS; // B*TV*UNITS floats

    proj_kernel<<<dim3(B * TQ / 4), 256, 0, stream>>>(query, w1, qproj, B * TQ);
    proj_kernel<<<dim3(B * TV / 4), 256, 0, stream>>>(value, w2, kproj, B * TV);
    attn_kernel<<<dim3(B * (TQ / QBLK)), NTHREADS, 0, stream>>>(qproj, kproj, value, scale,
                                                                out_ctx, out_attn);
}

// Round 3
// 92.508 us; speedup vs baseline: 2.6946x; 2.6946x over previous
//
#include <hip/hip_runtime.h>
#include <hip/hip_bf16.h>
#include <math.h>

#define B 4
#define TQ 512
#define TV 1024
#define DQ 256
#define DV 256
#define UNITS 64

#define CEXP  2.885390081777927f    // 2*log2(e): exp(2x) == exp2(CEXP*x)
#define LOG2E 1.4426950408889634f

__device__ __forceinline__ float fast_exp2(float x) {
#if __has_builtin(__builtin_amdgcn_exp2f)
    return __builtin_amdgcn_exp2f(x);
#else
    return __expf(0.6931471805599453f * x);
#endif
}

__device__ __forceinline__ float wave_max(float v) {
    #pragma unroll
    for (int off = 32; off > 0; off >>= 1)
        v = fmaxf(v, __shfl_xor(v, off, 64));
    return v;
}
__device__ __forceinline__ float wave_sum(float v) {
    #pragma unroll
    for (int off = 32; off > 0; off >>= 1)
        v += __shfl_xor(v, off, 64);
    return v;
}

// Both projections in one kernel; one wave per output row (lane = u).
// Outputs are pre-scaled by CEXP so the score kernel can use exp2 directly.
__global__ __launch_bounds__(256) void proj_kernel(
        const float* __restrict__ query, const float* __restrict__ value,
        const float* __restrict__ w1, const float* __restrict__ w2,
        float* __restrict__ qproj, float* __restrict__ kproj) {
    const int u = threadIdx.x & 63;
    int row = blockIdx.x * 4 + (threadIdx.x >> 6);
    const float* in; const float* w; float* out;
    if (row < B * TQ) {
        in = query + (size_t)row * DQ; w = w1; out = qproj + (size_t)row * UNITS;
    } else {
        row -= B * TQ;
        in = value + (size_t)row * DV; w = w2; out = kproj + (size_t)row * UNITS;
    }
    float acc = 0.f;
    #pragma unroll 8
    for (int d = 0; d < DQ; ++d)
        acc = fmaf(in[d], w[d * UNITS + u], acc);
    out[u] = acc * CEXP;
}

#define QB 2
// grid = B*TQ/QB = 1024 blocks, 256 threads
__global__ __launch_bounds__(256) void score_kernel(
        const float* __restrict__ qproj,   // [B*TQ, UNITS], pre-scaled
        const float* __restrict__ kproj,   // [B*TV, UNITS], pre-scaled
        const float* __restrict__ scale,   // [UNITS]
        float* __restrict__ out_attn) {    // [B*TQ, TV]
    __shared__ float q_lds[QB][UNITS];
    __shared__ float s_lds[UNITS];
    __shared__ float red[2][4];

    const int tid = threadIdx.x, lane = tid & 63, wid = tid >> 6;
    int bid = blockIdx.x;
    bid = (bid & 7) * ((B * TQ / QB) >> 3) + (bid >> 3);   // XCD swizzle, bijective
    const int b  = bid / (TQ / QB);
    const int q0 = (bid % (TQ / QB)) * QB;

    if (tid < QB * UNITS)
        q_lds[tid >> 6][tid & 63] =
            qproj[((size_t)(b * TQ + q0) + (tid >> 6)) * UNITS + (tid & 63)];
    else if (tid < QB * UNITS + UNITS)
        s_lds[tid - QB * UNITS] = scale[tid - QB * UNITS];
    __syncthreads();

    // ---- scores: thread owns v in {tid, tid+256, tid+512, tid+768} ----
    const float* kb = kproj + (size_t)b * TV * UNITS;
    float sc0[4], sc1[4];
    #pragma unroll 1
    for (int vi = 0; vi < 4; ++vi) {
        const int v = vi * 256 + tid;
        const float4* krow = (const float4*)(kb + (size_t)v * UNITS);
        const float4* qp0  = (const float4*)q_lds[0];
        const float4* qp1  = (const float4*)q_lds[1];
        const float4* sp   = (const float4*)s_lds;
        float a0 = 0.f, a1 = 0.f;
        #pragma unroll 4
        for (int c = 0; c < 16; ++c) {
            float4 k4 = krow[c];
            float4 qa = qp0[c], qb4 = qp1[c], s4 = sp[c];
            a0 = fmaf(s4.x, __builtin_amdgcn_rcpf(fast_exp2(qa.x  + k4.x) + 1.f), a0);
            a1 = fmaf(s4.x, __builtin_amdgcn_rcpf(fast_exp2(qb4.x + k4.x) + 1.f), a1);
            a0 = fmaf(s4.y, __builtin_amdgcn_rcpf(fast_exp2(qa.y  + k4.y) + 1.f), a0);
            a1 = fmaf(s4.y, __builtin_amdgcn_rcpf(fast_exp2(qb4.y + k4.y) + 1.f), a1);
            a0 = fmaf(s4.z, __builtin_amdgcn_rcpf(fast_exp2(qa.z  + k4.z) + 1.f), a0);
            a1 = fmaf(s4.z, __builtin_amdgcn_rcpf(fast_exp2(qb4.z + k4.z) + 1.f), a1);
            a0 = fmaf(s4.w, __builtin_amdgcn_rcpf(fast_exp2(qa.w  + k4.w) + 1.f), a0);
            a1 = fmaf(s4.w, __builtin_amdgcn_rcpf(fast_exp2(qb4.w + k4.w) + 1.f), a1);
        }
        // score = sum(scale) - 2a; softmax is shift-invariant -> use -2a
        sc0[vi] = -2.f * a0;
        sc1[vi] = -2.f * a1;
    }

    // ---- softmax (both q rows together) ----
    float m0 = fmaxf(fmaxf(sc0[0], sc0[1]), fmaxf(sc0[2], sc0[3]));
    float m1 = fmaxf(fmaxf(sc1[0], sc1[1]), fmaxf(sc1[2], sc1[3]));
    m0 = wave_max(m0); m1 = wave_max(m1);
    if (lane == 0) { red[0][wid] = m0; red[1][wid] = m1; }
    __syncthreads();
    m0 = fmaxf(fmaxf(red[0][0], red[0][1]), fmaxf(red[0][2], red[0][3]));
    m1 = fmaxf(fmaxf(red[1][0], red[1][1]), fmaxf(red[1][2], red[1][3]));

    float e0[4], e1[4], s0 = 0.f, s1 = 0.f;
    #pragma unroll
    for (int i = 0; i < 4; ++i) {
        e0[i] = fast_exp2((sc0[i] - m0) * LOG2E); s0 += e0[i];
        e1[i] = fast_exp2((sc1[i] - m1) * LOG2E); s1 += e1[i];
    }
    s0 = wave_sum(s0); s1 = wave_sum(s1);
    __syncthreads();                  // red max-reads done before overwrite
    if (lane == 0) { red[0][wid] = s0; red[1][wid] = s1; }
    __syncthreads();
    s0 = red[0][0] + red[0][1] + red[0][2] + red[0][3];
    s1 = red[1][0] + red[1][1] + red[1][2] + red[1][3];
    const float i0 = __builtin_amdgcn_rcpf(s0);
    const float i1 = __builtin_amdgcn_rcpf(s1);

    float* arow0 = out_attn + (size_t)(b * TQ + q0) * TV;
    float* arow1 = arow0 + TV;
    #pragma unroll
    for (int i = 0; i < 4; ++i) {
        arow0[i * 256 + tid] = e0[i] * i0;
        arow1[i * 256 + tid] = e1[i] * i1;
    }
}

#define QC 8
// grid = B*TQ/QC = 256 blocks, 512 threads
__global__ __launch_bounds__(512) void ctx_kernel(
        const float* __restrict__ attn,    // [B*TQ, TV]
        const float* __restrict__ value,   // [B, TV, DV]
        float* __restrict__ out_ctx) {     // [B*TQ, DV]
    __shared__ float a_lds[QC][TV];        // 32 KB

    const int tid = threadIdx.x;
    int bid = blockIdx.x;
    bid = (bid & 7) * ((B * TQ / QC) >> 3) + (bid >> 3);   // XCD swizzle
    const int b  = bid / (TQ / QC);
    const int q0 = (bid % (TQ / QC)) * QC;

    // stage attn rows (coalesced float4)
    const float4* src = (const float4*)(attn + (size_t)(b * TQ + q0) * TV);
    float4* dst = (float4*)a_lds;
    #pragma unroll
    for (int i = 0; i < (QC * TV / 4) / 512; ++i)   // 4 iters
        dst[tid + i * 512] = src[tid + i * 512];
    __syncthreads();

    const int d  = tid & (DV - 1);
    const int qh = (tid >> 8) * (QC / 2);  // 0 or 4
    const float* vb = value + (size_t)b * TV * DV + d;
    float acc[QC / 2] = {0.f, 0.f, 0.f, 0.f};
    #pragma unroll 2
    for (int v4 = 0; v4 < TV / 4; ++v4) {
        float4 aq[QC / 2];
        #pragma unroll
        for (int q = 0; q < QC / 2; ++q)
            aq[q] = ((const float4*)a_lds[qh + q])[v4];
        #pragma unroll
        for (int j = 0; j < 4; ++j) {
            float val = vb[(size_t)(v4 * 4 + j) * DV];
            #pragma unroll
            for (int q = 0; q < QC / 2; ++q)
                acc[q] = fmaf(((const float*)&aq[q])[j], val, acc[q]);
        }
    }
    #pragma unroll
    for (int q = 0; q < QC / 2; ++q)
        out_ctx[(size_t)(b * TQ + q0 + qh + q) * DV + d] = acc[q];
}

extern "C" void kernel_launch(void* const* d_in, const int* in_sizes, int n_in,
                              void* d_out, int out_size, void* d_ws, size_t ws_size,
                              hipStream_t stream) {
    const float* query = (const float*)d_in[0];
    const float* value = (const float*)d_in[1];
    const float* w1    = (const float*)d_in[2];
    const float* w2    = (const float*)d_in[3];
    const float* scale = (const float*)d_in[4];

    float* out      = (float*)d_out;
    float* out_ctx  = out;                         // [B*TQ*DV]
    float* out_attn = out + (size_t)B * TQ * DV;   // [B*TQ*TV]

    float* qproj = (float*)d_ws;                   // B*TQ*UNITS floats
    float* kproj = qproj + (size_t)B * TQ * UNITS; // B*TV*UNITS floats

    proj_kernel<<<dim3((B * TQ + B * TV) / 4), 256, 0, stream>>>(
        query, value, w1, w2, qproj, kproj);
    score_kernel<<<dim3(B * TQ / QB), 256, 0, stream>>>(qproj, kproj, scale, out_attn);
    ctx_kernel<<<dim3(B * TQ / QC), 512, 0, stream>>>(out_attn, value, out_ctx);
}

// Round 4
// 77.834 us; speedup vs baseline: 3.2027x; 1.1885x over previous
//
#include <hip/hip_runtime.h>
#include <math.h>

#define B 4
#define TQ 512
#define TV 1024
#define DQ 256
#define DV 256
#define UNITS 64

#define CEXP  2.885390081777927f    // 2*log2(e): exp(2x) == exp2(CEXP*x)
#define LOG2E 1.4426950408889634f

__device__ __forceinline__ float fast_exp2(float x) {
#if __has_builtin(__builtin_amdgcn_exp2f)
    return __builtin_amdgcn_exp2f(x);
#else
    return __expf(0.6931471805599453f * x);
#endif
}

__device__ __forceinline__ float wave_max(float v) {
    #pragma unroll
    for (int off = 32; off > 0; off >>= 1)
        v = fmaxf(v, __shfl_xor(v, off, 64));
    return v;
}
__device__ __forceinline__ float wave_sum(float v) {
    #pragma unroll
    for (int off = 32; off > 0; off >>= 1)
        v += __shfl_xor(v, off, 64);
    return v;
}

// Both projections; one wave per output row (lane = u).
// Writes Eq = exp2(CEXP*q), Ek = exp2(CEXP*k) so the score kernel needs no exp.
__global__ __launch_bounds__(256) void proj_kernel(
        const float* __restrict__ query, const float* __restrict__ value,
        const float* __restrict__ w1, const float* __restrict__ w2,
        float* __restrict__ Eq, float* __restrict__ Ek) {
    const int u = threadIdx.x & 63;
    int row = blockIdx.x * 4 + (threadIdx.x >> 6);
    const float* in; const float* w; float* out;
    if (row < B * TQ) {
        in = query + (size_t)row * DQ; w = w1; out = Eq + (size_t)row * UNITS;
    } else {
        row -= B * TQ;
        in = value + (size_t)row * DV; w = w2; out = Ek + (size_t)row * UNITS;
    }
    const float4* in4 = (const float4*)in;
    float a0 = 0.f, a1 = 0.f, a2 = 0.f, a3 = 0.f;
    #pragma unroll 8
    for (int c = 0; c < DQ / 4; ++c) {
        float4 t = in4[c];
        a0 = fmaf(t.x, w[(4 * c + 0) * UNITS + u], a0);
        a1 = fmaf(t.y, w[(4 * c + 1) * UNITS + u], a1);
        a2 = fmaf(t.z, w[(4 * c + 2) * UNITS + u], a2);
        a3 = fmaf(t.w, w[(4 * c + 3) * UNITS + u], a3);
    }
    out[u] = fast_exp2(CEXP * ((a0 + a1) + (a2 + a3)));
}

#define QB 4
#define SNT 512
// grid = B*TQ/QB = 512 blocks, 512 threads; each thread owns v = {tid, tid+512}
__global__ __launch_bounds__(SNT) void score_kernel(
        const float* __restrict__ Eq,      // [B*TQ, UNITS]
        const float* __restrict__ Ek,      // [B*TV, UNITS]
        const float* __restrict__ scale,   // [UNITS]
        float* __restrict__ out_attn) {    // [B*TQ, TV]
    __shared__ float q_lds[QB][UNITS];
    __shared__ float s_lds[UNITS];
    __shared__ float redm[QB][SNT / 64];
    __shared__ float reds[QB][SNT / 64];

    const int tid = threadIdx.x, lane = tid & 63, wid = tid >> 6;
    int bid = blockIdx.x;
    bid = (bid & 7) * ((B * TQ / QB) >> 3) + (bid >> 3);   // XCD swizzle, bijective
    const int b  = bid / (TQ / QB);
    const int q0 = (bid % (TQ / QB)) * QB;

    if (tid < QB * UNITS)
        q_lds[tid >> 6][tid & 63] =
            Eq[(size_t)(b * TQ + q0 + (tid >> 6)) * UNITS + (tid & 63)];
    else if (tid < QB * UNITS + UNITS)
        s_lds[tid - QB * UNITS] = scale[tid - QB * UNITS];
    __syncthreads();

    const float* kb = Ek + (size_t)b * TV * UNITS;
    const float4* krow0 = (const float4*)(kb + (size_t)tid * UNITS);
    const float4* krow1 = (const float4*)(kb + (size_t)(tid + SNT) * UNITS);
    const float4* qp = (const float4*)q_lds;     // [QB][16]
    const float4* sp = (const float4*)s_lds;

    float acc[QB][2] = {};
    #pragma unroll 4
    for (int c = 0; c < UNITS / 4; ++c) {
        float4 ea = krow0[c];
        float4 eb = krow1[c];
        float4 s4 = sp[c];
        #pragma unroll
        for (int q = 0; q < QB; ++q) {
            float4 eq = qp[q * (UNITS / 4) + c];
            float t, r;
            t = fmaf(eq.x, ea.x, 1.f); r = __builtin_amdgcn_rcpf(t); acc[q][0] = fmaf(s4.x, r, acc[q][0]);
            t = fmaf(eq.x, eb.x, 1.f); r = __builtin_amdgcn_rcpf(t); acc[q][1] = fmaf(s4.x, r, acc[q][1]);
            t = fmaf(eq.y, ea.y, 1.f); r = __builtin_amdgcn_rcpf(t); acc[q][0] = fmaf(s4.y, r, acc[q][0]);
            t = fmaf(eq.y, eb.y, 1.f); r = __builtin_amdgcn_rcpf(t); acc[q][1] = fmaf(s4.y, r, acc[q][1]);
            t = fmaf(eq.z, ea.z, 1.f); r = __builtin_amdgcn_rcpf(t); acc[q][0] = fmaf(s4.z, r, acc[q][0]);
            t = fmaf(eq.z, eb.z, 1.f); r = __builtin_amdgcn_rcpf(t); acc[q][1] = fmaf(s4.z, r, acc[q][1]);
            t = fmaf(eq.w, ea.w, 1.f); r = __builtin_amdgcn_rcpf(t); acc[q][0] = fmaf(s4.w, r, acc[q][0]);
            t = fmaf(eq.w, eb.w, 1.f); r = __builtin_amdgcn_rcpf(t); acc[q][1] = fmaf(s4.w, r, acc[q][1]);
        }
    }

    // scores (shift-invariant): x = -2 * acc
    float x[QB][2];
    #pragma unroll
    for (int q = 0; q < QB; ++q) {
        x[q][0] = -2.f * acc[q][0];
        x[q][1] = -2.f * acc[q][1];
    }

    // softmax over TV per q row
    float m[QB];
    #pragma unroll
    for (int q = 0; q < QB; ++q) {
        m[q] = wave_max(fmaxf(x[q][0], x[q][1]));
        if (lane == 0) redm[q][wid] = m[q];
    }
    __syncthreads();
    #pragma unroll
    for (int q = 0; q < QB; ++q) {
        float mm = redm[q][0];
        #pragma unroll
        for (int i = 1; i < SNT / 64; ++i) mm = fmaxf(mm, redm[q][i]);
        m[q] = mm;
    }
    float e[QB][2], s[QB];
    #pragma unroll
    for (int q = 0; q < QB; ++q) {
        const float mm = m[q] * LOG2E;
        e[q][0] = fast_exp2(fmaf(x[q][0], LOG2E, -mm));
        e[q][1] = fast_exp2(fmaf(x[q][1], LOG2E, -mm));
        s[q] = wave_sum(e[q][0] + e[q][1]);
        if (lane == 0) reds[q][wid] = s[q];
    }
    __syncthreads();
    #pragma unroll
    for (int q = 0; q < QB; ++q) {
        float ss = reds[q][0];
        #pragma unroll
        for (int i = 1; i < SNT / 64; ++i) ss += reds[q][i];
        const float inv = __builtin_amdgcn_rcpf(ss);
        float* arow = out_attn + (size_t)(b * TQ + q0 + q) * TV;
        arow[tid]       = e[q][0] * inv;
        arow[tid + SNT] = e[q][1] * inv;
    }
}

// context partial: each block does QC q-rows x TV/SPLIT v-range.
// attn row addresses are wave-uniform -> scalar/broadcast loads, no LDS.
template <int QC, int SPLIT>
__global__ __launch_bounds__(512) void ctx_kernel(
        const float* __restrict__ attn,    // [B*TQ, TV]
        const float* __restrict__ value,   // [B, TV, DV]
        float* __restrict__ dst) {         // [SPLIT][B*TQ, DV]
    constexpr int TVC = TV / SPLIT;
    constexpr int QT  = QC / 2;            // q rows per thread (512 thr / 256 d)
    const int tid = threadIdx.x;
    constexpr int G = (B * TQ / QC) * SPLIT;
    int bid = blockIdx.x;
    bid = (bid & 7) * (G >> 3) + (bid >> 3);   // XCD swizzle, bijective (G % 8 == 0)
    const int qc = bid / SPLIT, vs = bid % SPLIT;
    const int b  = qc / (TQ / QC);
    const int q0 = (qc % (TQ / QC)) * QC;
    const int v0 = vs * TVC;
    const int d  = tid & (DV - 1);
    const int qh = __builtin_amdgcn_readfirstlane(tid >> 8) * QT;

    const float* ab = attn + (size_t)(b * TQ + q0 + qh) * TV + v0;
    const float* vb = value + ((size_t)b * TV + v0) * DV + d;

    float acc[QT] = {};
    #pragma unroll 2
    for (int v4 = 0; v4 < TVC / 4; ++v4) {
        float4 aq[QT];
        #pragma unroll
        for (int j = 0; j < QT; ++j)
            aq[j] = *(const float4*)(ab + (size_t)j * TV + v4 * 4);
        #pragma unroll
        for (int k = 0; k < 4; ++k) {
            float val = vb[(size_t)(v4 * 4 + k) * DV];
            #pragma unroll
            for (int j = 0; j < QT; ++j)
                acc[j] = fmaf(((const float*)&aq[j])[k], val, acc[j]);
        }
    }
    float* o = dst + (size_t)vs * (B * TQ * DV) + (size_t)(b * TQ + q0 + qh) * DV + d;
    #pragma unroll
    for (int j = 0; j < QT; ++j)
        o[(size_t)j * DV] = acc[j];
}

// out[i] = sum over 4 partials
__global__ __launch_bounds__(256) void reduce_kernel(
        const float* __restrict__ part, float* __restrict__ out) {
    constexpr size_t S = (size_t)B * TQ * DV / 4;   // float4 count per partial
    const size_t i = (size_t)blockIdx.x * 256 + threadIdx.x;
    const float4* p = (const float4*)part;
    float4 a = p[i], b4 = p[i + S], c = p[i + 2 * S], d4 = p[i + 3 * S];
    float4 r;
    r.x = (a.x + b4.x) + (c.x + d4.x);
    r.y = (a.y + b4.y) + (c.y + d4.y);
    r.z = (a.z + b4.z) + (c.z + d4.z);
    r.w = (a.w + b4.w) + (c.w + d4.w);
    ((float4*)out)[i] = r;
}

extern "C" void kernel_launch(void* const* d_in, const int* in_sizes, int n_in,
                              void* d_out, int out_size, void* d_ws, size_t ws_size,
                              hipStream_t stream) {
    const float* query = (const float*)d_in[0];
    const float* value = (const float*)d_in[1];
    const float* w1    = (const float*)d_in[2];
    const float* w2    = (const float*)d_in[3];
    const float* scale = (const float*)d_in[4];

    float* out      = (float*)d_out;
    float* out_ctx  = out;                         // [B*TQ*DV]
    float* out_attn = out + (size_t)B * TQ * DV;   // [B*TQ*TV]

    float* Eq = (float*)d_ws;                      // B*TQ*UNITS floats
    float* Ek = Eq + (size_t)B * TQ * UNITS;       // B*TV*UNITS floats
    float* part = Ek + (size_t)B * TV * UNITS;     // 4 * B*TQ*DV floats

    const size_t need = ((size_t)(B * TQ + B * TV) * UNITS + (size_t)4 * B * TQ * DV)
                        * sizeof(float);

    proj_kernel<<<dim3((B * TQ + B * TV) / 4), 256, 0, stream>>>(
        query, value, w1, w2, Eq, Ek);
    score_kernel<<<dim3(B * TQ / QB), SNT, 0, stream>>>(Eq, Ek, scale, out_attn);
    if (ws_size >= need) {
        ctx_kernel<16, 4><<<dim3((B * TQ / 16) * 4), 512, 0, stream>>>(out_attn, value, part);
        reduce_kernel<<<dim3(B * TQ * DV / 4 / 256), 256, 0, stream>>>(part, out_ctx);
    } else {
        ctx_kernel<8, 1><<<dim3(B * TQ / 8), 512, 0, stream>>>(out_attn, value, out_ctx);
    }
}